// Round 4
// baseline (766.636 us; speedup 1.0000x reference)
//
#include <hip/hip_runtime.h>

#define BB 4096
#define SS 512
#define NG 256     // 4*HID gate columns
#define BT 16      // batch rows per workgroup (grid = 256 = #CUs)
#define NT 512     // threads per WG (8 waves, 2 per SIMD)
#define CH 32      // time-chunk length
#define HSTR 68    // hbuf row stride (shorts)
#define PSTR 16    // pcx row stride (shorts): slots 0..11 real, 12..15 zero
#define SBSTR 264  // sbias row stride (floats), overlaid on pcx
#define GSTR 66    // gexch row stride (floats)
#define OSTR 33    // obuf row stride (floats)

typedef __bf16 bf16_t;
typedef bf16_t bf16x8 __attribute__((ext_vector_type(8)));
typedef bf16_t bf16x2 __attribute__((ext_vector_type(2)));
typedef float  f32x4  __attribute__((ext_vector_type(4)));

__device__ __forceinline__ unsigned short f2bf(float x) {
    union { float f; unsigned u; } q{x};
    unsigned r = (q.u + 0x7fffu + ((q.u >> 16) & 1u)) >> 16;
    return (unsigned short)r;
}
__device__ __forceinline__ float bf2f(unsigned short s) {
    union { unsigned u; float f; } q{((unsigned)s) << 16};
    return q.f;
}
#define LOG2E 1.4426950408889634f
__device__ __forceinline__ float frcp_(float x)  { return __builtin_amdgcn_rcpf(x); }
__device__ __forceinline__ float fexp2_(float x) { return __builtin_amdgcn_exp2f(x); }
__device__ __forceinline__ float flog2_(float x) { return __builtin_amdgcn_logf(x); }
__device__ __forceinline__ float sigmoid_(float x) { return frcp_(1.0f + fexp2_(-LOG2E * x)); }
__device__ __forceinline__ float tanh_(float x)    { return 1.0f - 2.0f * frcp_(1.0f + fexp2_((2.0f * LOG2E) * x)); }
__device__ __forceinline__ float softplus_(float x){ return x > 20.0f ? x : 0.6931471805599453f * flog2_(1.0f + fexp2_(LOG2E * x)); }

// K-slot layout (96): 0..63 = h, 64 = prev, 65..74 = cov, 75 = prev residual, 76..95 = 0.
// 8 waves: wave w = (gp = w>>2, uu = w&3) owns gates {2gp, 2gp+1} for units 16uu..16uu+15
// (tiles 8gp+uu and 8gp+4+uu). Gates go through gexch; cell is 2 (row,unit) pairs/thread.
__global__ __launch_bounds__(NT)
void deepar_kernel(const float* __restrict__ target, const float* __restrict__ cov,
                   const int* __restrict__ cats, const float* __restrict__ scale,
                   const float* __restrict__ emb0, const float* __restrict__ emb1,
                   const float* __restrict__ emb2, const float* __restrict__ emb3,
                   const float* __restrict__ w_ih, const float* __restrict__ w_hh,
                   const float* __restrict__ bias, const float* __restrict__ w_out,
                   const float* __restrict__ b_out, float* __restrict__ out)
{
    // pcx (2*32*16*16 shorts = 32768 B) overlays sbias(16896 B)+sx(4352 B) scratch
    __shared__ __attribute__((aligned(16))) unsigned char smemA[2 * CH * BT * PSTR * 2];
    __shared__ __attribute__((aligned(16))) unsigned short hbuf[2][BT][HSTR]; //  4352 B
    __shared__ float gexch[4 * BT * GSTR];                                    // 16896 B
    __shared__ float obuf[2][CH][OSTR];                                       //  8448 B
    __shared__ float inv_s[BT], scl_s[BT];

    unsigned short* pcx   = (unsigned short*)smemA;
    float*          sbias = (float*)smemA;
    float*          sx    = (float*)(smemA + BT * SBSTR * 4);

    const int tid  = threadIdx.x;
    const int b0   = blockIdx.x * BT;
    const int lane = tid & 63;
    const int wv   = tid >> 6;
    const int qd   = lane >> 4;
    const int ln   = lane & 15;
    const int uu   = wv & 3;        // unit group (units 16uu..16uu+15)
    const int gp   = wv >> 2;       // gate pair (gates 2gp, 2gp+1)

    // ---------------- setup ----------------
    for (int i = tid; i < 2 * BT * HSTR; i += NT) ((unsigned short*)hbuf)[i] = 0;
    if (tid < BT) {
        float s = scale[b0 + tid];
        scl_s[tid] = s;
        inv_s[tid] = 1.0f / fmaxf(s, 1e-4f);
        sx[tid * 68 + 64] = log1pf(s);
    }
    if (tid < BT * 4) {
        int r = tid >> 2, e = tid & 3;
        int c = cats[(b0 + r) * 4 + e];
        const float* eb = (e == 0 ? emb0 : e == 1 ? emb1 : e == 2 ? emb2 : emb3);
        for (int j = 0; j < 16; ++j) sx[r * 68 + e * 16 + j] = eb[c * 16 + j];
    }
    __syncthreads();

    // sbias[r][n] = bias[n] + static_x[r] . w_ih[11..75][n]; n = tid&255, rows split by tid>>8
    {
        const int n = tid & 255, half = tid >> 8;
        float bj = bias[n];
        float acc[8];
        #pragma unroll
        for (int r = 0; r < 8; ++r) acc[r] = bj;
        for (int k = 0; k < 65; ++k) {
            float w = w_ih[(11 + k) * NG + n];
            #pragma unroll
            for (int r = 0; r < 8; ++r) acc[r] += sx[(half * 8 + r) * 68 + k] * w;
        }
        #pragma unroll
        for (int r = 0; r < 8; ++r) sbias[(half * 8 + r) * SBSTR + n] = acc[r];
    }
    __syncthreads();

    // ---------------- register-resident weights + sbias fragments ----------------
    bf16x8 bfrag[2][3];
    f32x4  sbf[2];
    #pragma unroll
    for (int ti = 0; ti < 2; ++ti) {
        const int tile = (2 * gp + ti) * 4 + uu;
        const int n = ln + 16 * tile;
        #pragma unroll
        for (int c = 0; c < 3; ++c) {
            #pragma unroll
            for (int j = 0; j < 8; ++j) {
                int k = qd * 8 + 32 * c + j;
                float w;
                if (k < 64)                  w = w_hh[k * NG + n];
                else if (k == 64 || k == 75) w = w_ih[n];
                else if (k <= 74)            w = w_ih[(k - 64) * NG + n];
                else                         w = 0.0f;
                bfrag[ti][c][j] = (bf16_t)w;
            }
        }
        #pragma unroll
        for (int r = 0; r < 4; ++r)
            sbf[ti][r] = sbias[(qd * 4 + r) * SBSTR + n];
    }

    // output head mapping (tid < 256: 16 rows x 2 outputs x 8 k-groups)
    const int prow = (tid >> 4) & 15, po = (tid >> 3) & 1, pkg = tid & 7;
    float wo[8];
    #pragma unroll
    for (int j = 0; j < 8; ++j) wo[j] = w_out[(pkg * 8 + j) * 2 + po];
    const float bo     = b_out[po];
    const float pscl   = (po == 0) ? scl_s[prow] : 1.0f;
    const int   opslot = po * 16 + prow;

    __syncthreads();   // all sbias/sx reads done -> safe to overwrite with pcx

    // zero pcx (both buffers; establishes the permanent-zero slots 12..15)
    for (int i = tid; i < (2 * CH * BT * PSTR) / 2; i += NT) ((int*)smemA)[i] = 0;
    __syncthreads();

    // fill pcx chunk 0 (steps 0..31): 32 threads per row, one step each
    {
        const int row = tid >> 5, i5 = tid & 31;
        const float* cr = cov + (size_t)(b0 + row) * (SS * 10);
        #pragma unroll
        for (int j = 0; j < 10; ++j) {
            int e = i5 + 32 * j, tp = e / 10, k = e - 10 * tp;
            pcx[((0 * CH + tp) * BT + row) * PSTR + 1 + k] = f2bf(cr[e]);
        }
        float pv = (i5 == 0) ? 0.0f : target[(size_t)(b0 + row) * SS + i5 - 1] * inv_s[row];
        unsigned short m = f2bf(pv);
        pcx[((0 * CH + i5) * BT + row) * PSTR + 0]  = m;
        pcx[((0 * CH + i5) * BT + row) * PSTR + 11] = f2bf(pv - bf2f(m));
    }

    // cell mapping: thread owns (crow, units cu, cu+1)
    const int crow = tid >> 5, cu = (tid & 31) * 2;
    float cst0 = 0.0f, cst1 = 0.0f;
    float crg[10];
    #pragma unroll
    for (int j = 0; j < 10; ++j) crg[j] = 0.0f;
    float trg = 0.0f;

    // ---------------- time loop ----------------
    for (int t = 0; t < SS; ++t) {
        const int cur = t & 1, nxt = cur ^ 1;
        __syncthreads();   // hbuf[cur]/pcx ready; gexch free

        // chunk start: issue global loads for chunk c+1 (committed 16 steps later)
        if ((t & 31) == 0 && t < 480) {
            const int t0n = t + CH;
            const float* cr = cov + (size_t)(b0 + crow) * (SS * 10) + t0n * 10;
            const int i5 = tid & 31;
            #pragma unroll
            for (int j = 0; j < 10; ++j) crg[j] = cr[i5 + 32 * j];
            trg = target[(size_t)(b0 + crow) * SS + t0n + i5 - 1];
        }

        // A fragments
        const unsigned short* hb = &hbuf[cur][ln][0];
        bf16x8 a0 = *(const bf16x8*)(hb + qd * 8);
        bf16x8 a1 = *(const bf16x8*)(hb + 32 + qd * 8);
        bf16x8 a2 = {};
        if (qd < 2)
            a2 = *(const bf16x8*)&pcx[((((t >> 5) & 1) * CH + (t & 31)) * BT + ln) * PSTR + qd * 8];

        f32x4 accA = __builtin_amdgcn_mfma_f32_16x16x32_bf16(a0, bfrag[0][0], sbf[0], 0, 0, 0);
        f32x4 accB = __builtin_amdgcn_mfma_f32_16x16x32_bf16(a0, bfrag[1][0], sbf[1], 0, 0, 0);
        accA = __builtin_amdgcn_mfma_f32_16x16x32_bf16(a1, bfrag[0][1], accA, 0, 0, 0);
        accB = __builtin_amdgcn_mfma_f32_16x16x32_bf16(a1, bfrag[1][1], accB, 0, 0, 0);
        accA = __builtin_amdgcn_mfma_f32_16x16x32_bf16(a2, bfrag[0][2], accA, 0, 0, 0);
        accB = __builtin_amdgcn_mfma_f32_16x16x32_bf16(a2, bfrag[1][2], accB, 0, 0, 0);

        // output head for step t-1 (independent of MFMA results; overlaps their latency)
        if (t > 0 && tid < 256) {
            bf16x8 hv = *(const bf16x8*)&hbuf[cur][prow][pkg * 8];
            float p = 0.0f;
            #pragma unroll
            for (int j = 0; j < 8; ++j) p += (float)hv[j] * wo[j];
            p += __shfl_xor(p, 1);
            p += __shfl_xor(p, 2);
            p += __shfl_xor(p, 4);
            if (pkg == 0) {
                float sp = softplus_(p + bo) + 1e-4f;
                obuf[((t - 1) >> 5) & 1][(t - 1) & 31][opslot] = sp * pscl;
            }
        }

        // publish gate accs: gexch[gate][row][unit]
        {
            const int gu = 16 * uu + ln;
            float* gbA = gexch + ((2 * gp) * BT) * GSTR + gu;
            float* gbB = gexch + ((2 * gp + 1) * BT) * GSTR + gu;
            #pragma unroll
            for (int r = 0; r < 4; ++r) {
                gbA[(qd * 4 + r) * GSTR] = accA[r];
                gbB[(qd * 4 + r) * GSTR] = accB[r];
            }
        }
        __syncthreads();   // gexch ready

        // mid-chunk: commit next pcx chunk from registers; flush previous obuf chunk
        if ((t & 31) == 16) {
            const int c = t >> 5;
            if (c < 15) {
                const int i5 = tid & 31, nb = (c + 1) & 1;
                float pv = trg * inv_s[crow];
                unsigned short m = f2bf(pv);
                pcx[((nb * CH + i5) * BT + crow) * PSTR + 0]  = m;
                pcx[((nb * CH + i5) * BT + crow) * PSTR + 11] = f2bf(pv - bf2f(m));
                #pragma unroll
                for (int j = 0; j < 10; ++j) {
                    int e = i5 + 32 * j, tp = e / 10, k = e - 10 * tp;
                    pcx[((nb * CH + tp) * BT + crow) * PSTR + 1 + k] = f2bf(crg[j]);
                }
            }
            if (c >= 1) {
                const int pb = (c - 1) & 1, t0p = (c - 1) << 5;
                #pragma unroll
                for (int h = 0; h < 2; ++h) {
                    int e = tid + NT * h;
                    int tte = e & 31, rowe = (e >> 5) & 15, pe = e >> 9;
                    out[(pe ? (BB * SS) : 0) + (size_t)(b0 + rowe) * SS + t0p + tte] =
                        obuf[pb][tte][pe * 16 + rowe];
                }
            }
        }

        // LSTM cell: 2 (row,unit) pairs per thread, gates from gexch
        {
            const float* gb = gexch + crow * GSTR + cu;
            float2 vi = *(const float2*)(gb + 0 * BT * GSTR);
            float2 vf = *(const float2*)(gb + 1 * BT * GSTR);
            float2 vg = *(const float2*)(gb + 2 * BT * GSTR);
            float2 vo = *(const float2*)(gb + 3 * BT * GSTR);
            float c0 = sigmoid_(vf.x) * cst0 + sigmoid_(vi.x) * tanh_(vg.x);
            float c1 = sigmoid_(vf.y) * cst1 + sigmoid_(vi.y) * tanh_(vg.y);
            cst0 = c0; cst1 = c1;
            float h0 = sigmoid_(vo.x) * tanh_(c0);
            float h1 = sigmoid_(vo.y) * tanh_(c1);
            bf16x2 hv; hv[0] = (bf16_t)h0; hv[1] = (bf16_t)h1;
            *(bf16x2*)&hbuf[nxt][crow][cu] = hv;
        }
    }

    // ---------------- epilogue: head for t=511 (h in hbuf[0]) + flush chunk 15 ----------------
    __syncthreads();
    if (tid < 256) {
        bf16x8 hv = *(const bf16x8*)&hbuf[0][prow][pkg * 8];
        float p = 0.0f;
        #pragma unroll
        for (int j = 0; j < 8; ++j) p += (float)hv[j] * wo[j];
        p += __shfl_xor(p, 1);
        p += __shfl_xor(p, 2);
        p += __shfl_xor(p, 4);
        if (pkg == 0) {
            float sp = softplus_(p + bo) + 1e-4f;
            obuf[1][31][opslot] = sp * pscl;
        }
    }
    __syncthreads();
    #pragma unroll
    for (int h = 0; h < 2; ++h) {
        int e = tid + NT * h;
        int tte = e & 31, rowe = (e >> 5) & 15, pe = e >> 9;
        out[(pe ? (BB * SS) : 0) + (size_t)(b0 + rowe) * SS + 480 + tte] =
            obuf[1][tte][pe * 16 + rowe];
    }
}

extern "C" void kernel_launch(void* const* d_in, const int* in_sizes, int n_in,
                              void* d_out, int out_size, void* d_ws, size_t ws_size,
                              hipStream_t stream) {
    deepar_kernel<<<BB / BT, NT, 0, stream>>>(
        (const float*)d_in[0], (const float*)d_in[1], (const int*)d_in[2],
        (const float*)d_in[3], (const float*)d_in[4], (const float*)d_in[5],
        (const float*)d_in[6], (const float*)d_in[7], (const float*)d_in[8],
        (const float*)d_in[9], (const float*)d_in[10], (const float*)d_in[11],
        (const float*)d_in[12], (float*)d_out);
}

// Round 5
// 500.234 us; speedup vs baseline: 1.5326x; 1.5326x over previous
//
#include <hip/hip_runtime.h>

#define BB 4096
#define SS 512
#define NG 256     // 4*HID gate columns
#define BT 16      // batch rows per workgroup (grid = 256 = #CUs)
#define NT 512     // 8 waves: 0-3 compute (MFMA+cell), 4-7 service (head/stage/flush)
#define CH 32      // time-chunk length
#define HSTR 68    // hbuf row stride (shorts)
#define PSTR 16    // pcx row stride (shorts): slots 0..11 real, 12..15 zero
#define SBSTR 264  // sbias row stride (floats), overlaid on pcx
#define OSTR 33    // obuf row stride (floats)

typedef __bf16 bf16_t;
typedef bf16_t bf16x8 __attribute__((ext_vector_type(8)));
typedef float  f32x4  __attribute__((ext_vector_type(4)));

__device__ __forceinline__ unsigned short f2bf(float x) {
    union { float f; unsigned u; } q{x};
    unsigned r = (q.u + 0x7fffu + ((q.u >> 16) & 1u)) >> 16;
    return (unsigned short)r;
}
__device__ __forceinline__ float bf2f(unsigned short s) {
    union { unsigned u; float f; } q{((unsigned)s) << 16};
    return q.f;
}
#define LOG2E 1.4426950408889634f
__device__ __forceinline__ float frcp_(float x)  { return __builtin_amdgcn_rcpf(x); }
__device__ __forceinline__ float fexp2_(float x) { return __builtin_amdgcn_exp2f(x); }
__device__ __forceinline__ float flog2_(float x) { return __builtin_amdgcn_logf(x); }
__device__ __forceinline__ float sigmoid_(float x) { return frcp_(1.0f + fexp2_(-LOG2E * x)); }
__device__ __forceinline__ float tanh_(float x)    { return 1.0f - 2.0f * frcp_(1.0f + fexp2_((2.0f * LOG2E) * x)); }
__device__ __forceinline__ float softplus_(float x){ return x > 20.0f ? x : 0.6931471805599453f * flog2_(1.0f + fexp2_(LOG2E * x)); }

// K-slot layout (96): 0..63 = h, 64 = prev, 65..74 = cov, 75 = prev residual, 76..95 = 0.
// Waves 0-3: wave wv owns all 4 gates for units 16wv..16wv+15 (tiles wv+4g);
// cell is lane-local (unit = 16wv+ln, rows qd*4+r). One barrier per step.
__global__ __launch_bounds__(NT)
void deepar_kernel(const float* __restrict__ target, const float* __restrict__ cov,
                   const int* __restrict__ cats, const float* __restrict__ scale,
                   const float* __restrict__ emb0, const float* __restrict__ emb1,
                   const float* __restrict__ emb2, const float* __restrict__ emb3,
                   const float* __restrict__ w_ih, const float* __restrict__ w_hh,
                   const float* __restrict__ bias, const float* __restrict__ w_out,
                   const float* __restrict__ b_out, float* __restrict__ out)
{
    // pcx (2*32*16*16 shorts = 32768 B) overlays sbias(16896 B)+sx(4352 B) scratch
    __shared__ __attribute__((aligned(16))) unsigned char smemA[2 * CH * BT * PSTR * 2];
    __shared__ __attribute__((aligned(16))) unsigned short hbuf[2][BT][HSTR]; //  4352 B
    __shared__ float obuf[2][CH][OSTR];                                       //  8448 B
    __shared__ float inv_s[BT], scl_s[BT];

    unsigned short* pcx   = (unsigned short*)smemA;
    float*          sbias = (float*)smemA;
    float*          sx    = (float*)(smemA + BT * SBSTR * 4);

    const int tid  = threadIdx.x;
    const int b0   = blockIdx.x * BT;
    const int lane = tid & 63;
    const int wv   = tid >> 6;
    const int qd   = lane >> 4;
    const int ln   = lane & 15;
    const bool is_compute = (wv < 4);
    const int tid2 = tid & 255;          // index within service half (wv>=4)

    // ---------------- setup ----------------
    for (int i = tid; i < 2 * BT * HSTR; i += NT) ((unsigned short*)hbuf)[i] = 0;
    if (tid < BT) {
        float s = scale[b0 + tid];
        scl_s[tid] = s;
        inv_s[tid] = 1.0f / fmaxf(s, 1e-4f);
        sx[tid * 68 + 64] = log1pf(s);
    }
    if (tid < BT * 4) {
        int r = tid >> 2, e = tid & 3;
        int c = cats[(b0 + r) * 4 + e];
        const float* eb = (e == 0 ? emb0 : e == 1 ? emb1 : e == 2 ? emb2 : emb3);
        for (int j = 0; j < 16; ++j) sx[r * 68 + e * 16 + j] = eb[c * 16 + j];
    }
    __syncthreads();

    // sbias[r][n] = bias[n] + static_x[r] . w_ih[11..75][n]; n = tid&255, rows split by tid>>8
    {
        const int n = tid & 255, half = tid >> 8;
        float bj = bias[n];
        float acc[8];
        #pragma unroll
        for (int r = 0; r < 8; ++r) acc[r] = bj;
        for (int k = 0; k < 65; ++k) {
            float w = w_ih[(11 + k) * NG + n];
            #pragma unroll
            for (int r = 0; r < 8; ++r) acc[r] += sx[(half * 8 + r) * 68 + k] * w;
        }
        #pragma unroll
        for (int r = 0; r < 8; ++r) sbias[(half * 8 + r) * SBSTR + n] = acc[r];
    }
    __syncthreads();

    // ---------------- register-resident weights + sbias fragments (compute waves) ----------------
    bf16x8 bfrag[4][3];
    f32x4  sbf[4];
    if (is_compute) {
        #pragma unroll
        for (int ti = 0; ti < 4; ++ti) {
            const int n = ln + 16 * (wv + 4 * ti);   // gate ti, unit 16wv+ln
            #pragma unroll
            for (int c = 0; c < 3; ++c) {
                #pragma unroll
                for (int j = 0; j < 8; ++j) {
                    int k = qd * 8 + 32 * c + j;
                    float w;
                    if (k < 64)                  w = w_hh[k * NG + n];
                    else if (k == 64 || k == 75) w = w_ih[n];
                    else if (k <= 74)            w = w_ih[(k - 64) * NG + n];
                    else                         w = 0.0f;
                    bfrag[ti][c][j] = (bf16_t)w;
                }
            }
            #pragma unroll
            for (int r = 0; r < 4; ++r)
                sbf[ti][r] = sbias[(qd * 4 + r) * SBSTR + n];
        }
    }

    // output head mapping (service waves: 16 rows x 2 outputs x 8 k-groups over tid2)
    const int prow = (tid2 >> 4) & 15, po = (tid2 >> 3) & 1, pkg = tid2 & 7;
    float wo[8];
    float bo = 0.0f, pscl = 1.0f;
    int opslot = 0;
    if (!is_compute) {
        #pragma unroll
        for (int j = 0; j < 8; ++j) wo[j] = w_out[(pkg * 8 + j) * 2 + po];
        bo     = b_out[po];
        pscl   = (po == 0) ? scl_s[prow] : 1.0f;
        opslot = po * 16 + prow;
    }

    __syncthreads();   // all sbias/sx reads done -> safe to overwrite with pcx

    // zero pcx (both buffers; establishes the permanent-zero slots 12..15)
    for (int i = tid; i < (2 * CH * BT * PSTR) / 2; i += NT) ((int*)smemA)[i] = 0;
    __syncthreads();

    // fill pcx chunk 0 (steps 0..31): 256 threads, row = tid>>4, two 16-step halves
    if (tid < 256) {
        const int row = tid >> 4, i5 = tid & 15;
        const float* cr = cov + (size_t)(b0 + row) * (SS * 10);
        #pragma unroll
        for (int j = 0; j < 20; ++j) {
            int e = i5 + 16 * j, tp = e / 10, k = e - 10 * tp;
            pcx[((0 * CH + tp) * BT + row) * PSTR + 1 + k] = f2bf(cr[e]);
        }
        float pv0 = (i5 == 0) ? 0.0f : target[(size_t)(b0 + row) * SS + i5 - 1] * inv_s[row];
        float pv1 = target[(size_t)(b0 + row) * SS + i5 + 15] * inv_s[row];
        unsigned short m0 = f2bf(pv0), m1 = f2bf(pv1);
        pcx[((0 * CH + i5) * BT + row) * PSTR + 0]       = m0;
        pcx[((0 * CH + i5) * BT + row) * PSTR + 11]      = f2bf(pv0 - bf2f(m0));
        pcx[((0 * CH + i5 + 16) * BT + row) * PSTR + 0]  = m1;
        pcx[((0 * CH + i5 + 16) * BT + row) * PSTR + 11] = f2bf(pv1 - bf2f(m1));
    }
    __syncthreads();

    // prime a2 for t = 0 (compute waves)
    bf16x8 a2 = {};
    if (is_compute && qd < 2)
        a2 = *(const bf16x8*)&pcx[((0 * CH + 0) * BT + ln) * PSTR + qd * 8];

    float cst[4] = {0.0f, 0.0f, 0.0f, 0.0f};
    float crg[20];
    #pragma unroll
    for (int j = 0; j < 20; ++j) crg[j] = 0.0f;
    float trg0 = 0.0f, trg1 = 0.0f;

    // ---------------- time loop (ONE barrier per step) ----------------
    for (int t = 0; t < SS; ++t) {
        const int cur = t & 1, nxt = cur ^ 1;
        __syncthreads();   // hbuf[cur] complete; a2 already in registers

        if (is_compute) {
            // ---- recurrence waves: LDS + MFMA + cell only ----
            const unsigned short* hb = &hbuf[cur][ln][0];
            bf16x8 a0 = *(const bf16x8*)(hb + qd * 8);
            bf16x8 a1 = *(const bf16x8*)(hb + 32 + qd * 8);

            f32x4 acc0 = __builtin_amdgcn_mfma_f32_16x16x32_bf16(a0, bfrag[0][0], sbf[0], 0, 0, 0);
            f32x4 acc1 = __builtin_amdgcn_mfma_f32_16x16x32_bf16(a0, bfrag[1][0], sbf[1], 0, 0, 0);
            f32x4 acc2 = __builtin_amdgcn_mfma_f32_16x16x32_bf16(a0, bfrag[2][0], sbf[2], 0, 0, 0);
            f32x4 acc3 = __builtin_amdgcn_mfma_f32_16x16x32_bf16(a0, bfrag[3][0], sbf[3], 0, 0, 0);
            acc0 = __builtin_amdgcn_mfma_f32_16x16x32_bf16(a1, bfrag[0][1], acc0, 0, 0, 0);
            acc1 = __builtin_amdgcn_mfma_f32_16x16x32_bf16(a1, bfrag[1][1], acc1, 0, 0, 0);
            acc2 = __builtin_amdgcn_mfma_f32_16x16x32_bf16(a1, bfrag[2][1], acc2, 0, 0, 0);
            acc3 = __builtin_amdgcn_mfma_f32_16x16x32_bf16(a1, bfrag[3][1], acc3, 0, 0, 0);
            acc0 = __builtin_amdgcn_mfma_f32_16x16x32_bf16(a2, bfrag[0][2], acc0, 0, 0, 0);
            acc1 = __builtin_amdgcn_mfma_f32_16x16x32_bf16(a2, bfrag[1][2], acc1, 0, 0, 0);
            acc2 = __builtin_amdgcn_mfma_f32_16x16x32_bf16(a2, bfrag[2][2], acc2, 0, 0, 0);
            acc3 = __builtin_amdgcn_mfma_f32_16x16x32_bf16(a2, bfrag[3][2], acc3, 0, 0, 0);

            // prefetch a2 for t+1 (pcx for t+1 is stable: committed >=15 steps earlier)
            if (t + 1 < SS && qd < 2)
                a2 = *(const bf16x8*)&pcx[((((t + 1) >> 5) & 1) * CH + ((t + 1) & 31)) * BT * PSTR
                                          + ln * PSTR + qd * 8];

            // lane-local LSTM cell: unit u = 16wv+ln, rows qd*4+r
            const int u = 16 * wv + ln;
            #pragma unroll
            for (int r = 0; r < 4; ++r) {
                float ig = sigmoid_(acc0[r]);
                float fg = sigmoid_(acc1[r]);
                float gg = tanh_(acc2[r]);
                float og = sigmoid_(acc3[r]);
                float cc = fg * cst[r] + ig * gg;
                cst[r] = cc;
                hbuf[nxt][qd * 4 + r][u] = f2bf(og * tanh_(cc));
            }
        } else {
            // ---- service waves: head(t-1), staging, flush ----
            if ((t & 31) == 0 && t < 480) {
                const int row = tid2 >> 4, i5 = tid2 & 15, t0n = t + CH;
                const float* cr = cov + (size_t)(b0 + row) * (SS * 10) + t0n * 10;
                #pragma unroll
                for (int j = 0; j < 20; ++j) crg[j] = cr[i5 + 16 * j];
                const float* tr = target + (size_t)(b0 + row) * SS + t0n + i5;
                trg0 = tr[-1];
                trg1 = tr[15];
            }

            if (t > 0) {
                bf16x8 hv = *(const bf16x8*)&hbuf[cur][prow][pkg * 8];
                float p = 0.0f;
                #pragma unroll
                for (int j = 0; j < 8; ++j) p += (float)hv[j] * wo[j];
                p += __shfl_xor(p, 1);
                p += __shfl_xor(p, 2);
                p += __shfl_xor(p, 4);
                if (pkg == 0) {
                    float sp = softplus_(p + bo) + 1e-4f;
                    obuf[((t - 1) >> 5) & 1][(t - 1) & 31][opslot] = sp * pscl;
                }
            }

            if ((t & 31) == 16) {
                const int c = t >> 5;
                if (c < 15) {
                    const int row = tid2 >> 4, i5 = tid2 & 15, nb = (c + 1) & 1;
                    float pv0 = trg0 * inv_s[row];
                    float pv1 = trg1 * inv_s[row];
                    unsigned short m0 = f2bf(pv0), m1 = f2bf(pv1);
                    pcx[((nb * CH + i5) * BT + row) * PSTR + 0]       = m0;
                    pcx[((nb * CH + i5) * BT + row) * PSTR + 11]      = f2bf(pv0 - bf2f(m0));
                    pcx[((nb * CH + i5 + 16) * BT + row) * PSTR + 0]  = m1;
                    pcx[((nb * CH + i5 + 16) * BT + row) * PSTR + 11] = f2bf(pv1 - bf2f(m1));
                    #pragma unroll
                    for (int j = 0; j < 20; ++j) {
                        int e = i5 + 16 * j, tp = e / 10, k = e - 10 * tp;
                        pcx[((nb * CH + tp) * BT + row) * PSTR + 1 + k] = f2bf(crg[j]);
                    }
                }
                if (c >= 1) {
                    const int pb = (c - 1) & 1, t0p = (c - 1) << 5;
                    #pragma unroll
                    for (int h = 0; h < 4; ++h) {
                        int e = tid2 + 256 * h;
                        int tte = e & 31, rowe = (e >> 5) & 15, pe = e >> 9;
                        out[(pe ? (BB * SS) : 0) + (size_t)(b0 + rowe) * SS + t0p + tte] =
                            obuf[pb][tte][pe * 16 + rowe];
                    }
                }
            }
        }
    }

    // ---------------- epilogue: head for t=511 (h in hbuf[0]) + flush chunk 15 ----------------
    __syncthreads();
    if (!is_compute) {
        bf16x8 hv = *(const bf16x8*)&hbuf[0][prow][pkg * 8];
        float p = 0.0f;
        #pragma unroll
        for (int j = 0; j < 8; ++j) p += (float)hv[j] * wo[j];
        p += __shfl_xor(p, 1);
        p += __shfl_xor(p, 2);
        p += __shfl_xor(p, 4);
        if (pkg == 0) {
            float sp = softplus_(p + bo) + 1e-4f;
            obuf[1][31][opslot] = sp * pscl;
        }
    }
    __syncthreads();
    #pragma unroll
    for (int h = 0; h < 2; ++h) {
        int e = tid + NT * h;
        int tte = e & 31, rowe = (e >> 5) & 15, pe = e >> 9;
        out[(pe ? (BB * SS) : 0) + (size_t)(b0 + rowe) * SS + 480 + tte] =
            obuf[1][tte][pe * 16 + rowe];
    }
}

extern "C" void kernel_launch(void* const* d_in, const int* in_sizes, int n_in,
                              void* d_out, int out_size, void* d_ws, size_t ws_size,
                              hipStream_t stream) {
    deepar_kernel<<<BB / BT, NT, 0, stream>>>(
        (const float*)d_in[0], (const float*)d_in[1], (const int*)d_in[2],
        (const float*)d_in[3], (const float*)d_in[4], (const float*)d_in[5],
        (const float*)d_in[6], (const float*)d_in[7], (const float*)d_in[8],
        (const float*)d_in[9], (const float*)d_in[10], (const float*)d_in[11],
        (const float*)d_in[12], (float*)d_out);
}